// Round 4
// baseline (585.581 us; speedup 1.0000x reference)
//
#include <hip/hip_runtime.h>
#include <math.h>

typedef unsigned short u16;
typedef short s16x8 __attribute__((ext_vector_type(8)));
typedef float f32x4 __attribute__((ext_vector_type(4)));
typedef u16 u16x4 __attribute__((ext_vector_type(4)));
typedef u16 u16x8 __attribute__((ext_vector_type(8)));
typedef int i32x4 __attribute__((ext_vector_type(4)));

#define D 1024
#define MM 2048   // B*S
#define HH 512
#define VV 32000

static __device__ __forceinline__ u16 f2bf(float f) {
    union { float f; unsigned int i; } c; c.f = f;
    unsigned int x = c.i;
    return (u16)((x + 0x7fffu + ((x >> 16) & 1u)) >> 16);  // RNE
}
static __device__ __forceinline__ float sigm(float x) { return 1.0f / (1.0f + expf(-x)); }

// ---------------- embed: h = embedding[ids] + pos (all f32) ----------------
__global__ __launch_bounds__(256) void embed_kernel(const int* __restrict__ ids,
    const float* __restrict__ emb, const float* __restrict__ pos, float* __restrict__ h)
{
    const int m = blockIdx.x;            // 0..2047
    const int s = m & 1023;              // S = 1024
    const long id = ids[m];
    const int d = threadIdx.x * 4;
    f32x4 ev = *(const f32x4*)&emb[id * D + d];
    f32x4 pv = *(const f32x4*)&pos[(long)s * D + d];
    f32x4 o;
#pragma unroll
    for (int i = 0; i < 4; i++) o[i] = ev[i] + pv[i];
    *(f32x4*)&h[(long)m * D + d] = o;
}

// ---------------- layernorm(f32 in) -> bf16 out ----------------
__global__ __launch_bounds__(256) void ln_bf16_kernel(const float* __restrict__ h,
    u16* __restrict__ out, const float* __restrict__ g, const float* __restrict__ b)
{
    const int row = blockIdx.x;
    const int d = threadIdx.x * 4;
    f32x4 x = *(const f32x4*)&h[(long)row * D + d];
    float s = x[0] + x[1] + x[2] + x[3];
    float ss = x[0]*x[0] + x[1]*x[1] + x[2]*x[2] + x[3]*x[3];
#pragma unroll
    for (int off = 32; off; off >>= 1) { s += __shfl_xor(s, off); ss += __shfl_xor(ss, off); }
    __shared__ float red[8];
    const int wid = threadIdx.x >> 6;
    if ((threadIdx.x & 63) == 0) { red[wid] = s; red[4 + wid] = ss; }
    __syncthreads();
    s = red[0] + red[1] + red[2] + red[3];
    ss = red[4] + red[5] + red[6] + red[7];
    const float mu = s * (1.0f / D);
    const float rstd = rsqrtf(ss * (1.0f / D) - mu * mu + 1e-5f);
    f32x4 gv = *(const f32x4*)&g[d];
    f32x4 bv = *(const f32x4*)&b[d];
    u16x4 o;
#pragma unroll
    for (int i = 0; i < 4; i++) o[i] = f2bf((x[i] - mu) * rstd * gv[i] + bv[i]);
    *(u16x4*)&out[(long)row * D + d] = o;
}

// ---------------- h = LN(h + 0.3*C) (f32 in place) ----------------
__global__ __launch_bounds__(256) void resln_kernel(float* __restrict__ h,
    const float* __restrict__ c, const float* __restrict__ g, const float* __restrict__ b)
{
    const int row = blockIdx.x;
    const int d = threadIdx.x * 4;
    f32x4 x = *(const f32x4*)&h[(long)row * D + d];
    f32x4 cv = *(const f32x4*)&c[(long)row * D + d];
#pragma unroll
    for (int i = 0; i < 4; i++) x[i] += 0.3f * cv[i];
    float s = x[0] + x[1] + x[2] + x[3];
    float ss = x[0]*x[0] + x[1]*x[1] + x[2]*x[2] + x[3]*x[3];
#pragma unroll
    for (int off = 32; off; off >>= 1) { s += __shfl_xor(s, off); ss += __shfl_xor(ss, off); }
    __shared__ float red[8];
    const int wid = threadIdx.x >> 6;
    if ((threadIdx.x & 63) == 0) { red[wid] = s; red[4 + wid] = ss; }
    __syncthreads();
    s = red[0] + red[1] + red[2] + red[3];
    ss = red[4] + red[5] + red[6] + red[7];
    const float mu = s * (1.0f / D);
    const float rstd = rsqrtf(ss * (1.0f / D) - mu * mu + 1e-5f);
    f32x4 gv = *(const f32x4*)&g[d];
    f32x4 bv = *(const f32x4*)&b[d];
    f32x4 o;
#pragma unroll
    for (int i = 0; i < 4; i++) o[i] = (x[i] - mu) * rstd * gv[i] + bv[i];
    *(f32x4*)&h[(long)row * D + d] = o;
}

// ---------------- exc scales: sc[k] = exc_k / sum(exc) ----------------
__global__ void exc_kernel(const float* __restrict__ pW, const float* __restrict__ pb,
                           float* __restrict__ sc)
{
    if (threadIdx.x == 0 && blockIdx.x == 0) {
        const float NS = 1.0f / (1.0f + expf(-0.70710678118654752f)); // sigmoid(neighbor infl)
        float e[4], sum = 0.0f;
        for (int k = 0; k < 4; k++) {
            float a = pb[k];
            for (int j = 0; j < 4; j++) a += 0.5f * pW[k * 4 + j];
            e[k] = 0.6f * sigm(a) + 0.4f * NS;
            sum += e[k];
        }
        for (int k = 0; k < 4; k++) sc[k] = e[k] / sum;
    }
}

// ---------------- W2eff[n][k*512+h] = W2[k][n][h] * sigmoid(gate[k][n]+tors[n]) * sc[k] ----------------
__global__ __launch_bounds__(256) void scale_w2_kernel(
    const float* __restrict__ W2l,   // [4][1024][512] f32
    const float* __restrict__ gatel, // [4][1024] f32
    const float* __restrict__ tors,  // [1024] f32
    const float* __restrict__ sc,    // [4]
    u16* __restrict__ W2eff)         // [1024][2048] bf16
{
    const int n = blockIdx.x >> 1;
    const int half = blockIdx.x & 1;
    const int kh = half * 1024 + threadIdx.x * 4;
    const int k = kh >> 9;
    const int hh = kh & 511;
    const float f = sigm(gatel[k * D + n] + tors[n]) * sc[k];
    f32x4 w = *(const f32x4*)&W2l[((long)k * D + n) * HH + hh];
    u16x4 o;
#pragma unroll
    for (int i = 0; i < 4; i++) o[i] = f2bf(w[i] * f);
    *(u16x4*)&W2eff[(long)n * 2048 + kh] = o;
}

// ---------------- GEMM: C[M,N] = A[M,K] @ W[N,K]^T  (A bf16; W bf16 or f32->bf16 inline) ----------------
// EPI: 0 = f32 store, 1 = exact-GELU -> bf16 store, 2 = f32 accumulate (+=)
template<int EPI, bool WF32>
__global__ __launch_bounds__(256) void gemm_kernel(
    const u16* __restrict__ A, const void* __restrict__ Wv,
    float* __restrict__ Cf, u16* __restrict__ Cb,
    const int N, const int K, const long ldc,
    const long strideWz, const long strideCz)
{
    const u16*   Wb = WF32 ? nullptr : ((const u16*)Wv)   + (long)blockIdx.z * strideWz;
    const float* Wf = WF32 ? ((const float*)Wv) + (long)blockIdx.z * strideWz : nullptr;
    if (EPI == 1) Cb += (long)blockIdx.z * strideCz;
    else          Cf += (long)blockIdx.z * strideCz;

    const int bm = blockIdx.x * 128;
    const int bn = blockIdx.y * 128;

    __shared__ __align__(16) u16 As[128][40];   // +8 pad: row stride 80B kills phase conflicts
    __shared__ __align__(16) u16 Bs[128][40];

    const int tid = threadIdx.x;
    const int lane = tid & 63;
    const int wid = tid >> 6;
    const int wm = (wid >> 1) * 64;   // waves 2x2 over the 128x128 tile
    const int wn = (wid & 1) * 64;
    const int lr = lane & 15;
    const int lk = (lane >> 4) * 8;   // 8 contiguous k per lane (16x16x32 layout)

    const int srow = tid >> 2;
    const int scol = (tid & 3) * 8;

    f32x4 acc[4][4] = {};

    for (int k0 = 0; k0 < K; k0 += 32) {
        __syncthreads();
#pragma unroll
        for (int p = 0; p < 2; p++) {
            const int r = srow + p * 64;
            *(i32x4*)&As[r][scol] = *(const i32x4*)&A[(long)(bm + r) * K + k0 + scol];
            if (WF32) {
                f32x4 w0 = *(const f32x4*)&Wf[(long)(bn + r) * K + k0 + scol];
                f32x4 w1 = *(const f32x4*)&Wf[(long)(bn + r) * K + k0 + scol + 4];
                u16x8 wb;
#pragma unroll
                for (int i = 0; i < 4; i++) { wb[i] = f2bf(w0[i]); wb[4 + i] = f2bf(w1[i]); }
                *(u16x8*)&Bs[r][scol] = wb;
            } else {
                *(i32x4*)&Bs[r][scol] = *(const i32x4*)&Wb[(long)(bn + r) * K + k0 + scol];
            }
        }
        __syncthreads();
        s16x8 a[4], b[4];
#pragma unroll
        for (int i = 0; i < 4; i++) a[i] = *(const s16x8*)&As[wm + i * 16 + lr][lk];
#pragma unroll
        for (int j = 0; j < 4; j++) b[j] = *(const s16x8*)&Bs[wn + j * 16 + lr][lk];
#pragma unroll
        for (int i = 0; i < 4; i++)
#pragma unroll
            for (int j = 0; j < 4; j++)
                acc[i][j] = __builtin_amdgcn_mfma_f32_16x16x32_bf16(a[i], b[j], acc[i][j], 0, 0, 0);
    }

    // C/D layout (verified m89/m91): col = lane&15, row = (lane>>4)*4 + reg
    const int r0 = (lane >> 4) * 4;
#pragma unroll
    for (int i = 0; i < 4; i++) {
#pragma unroll
        for (int j = 0; j < 4; j++) {
            const int n = bn + wn + j * 16 + lr;
#pragma unroll
            for (int r = 0; r < 4; r++) {
                const int m = bm + wm + i * 16 + r0 + r;
                const float v = acc[i][j][r];
                if (EPI == 0) {
                    Cf[(long)m * ldc + n] = v;
                } else if (EPI == 1) {
                    const float gel = 0.5f * v * (1.0f + erff(v * 0.70710678118654752f));
                    Cb[(long)m * ldc + n] = f2bf(gel);
                } else {
                    Cf[(long)m * ldc + n] += v;
                }
            }
        }
    }
}

extern "C" void kernel_launch(void* const* d_in, const int* in_sizes, int n_in,
                              void* d_out, int out_size, void* d_ws, size_t ws_size,
                              hipStream_t stream)
{
    (void)in_sizes; (void)n_in; (void)out_size; (void)ws_size;
    const int*   ids   = (const int*)d_in[0];
    const float* emb   = (const float*)d_in[1];
    const float* pos   = (const float*)d_in[2];
    const float* tors  = (const float*)d_in[3];
    const float* ln1g  = (const float*)d_in[4];
    const float* ln1b  = (const float*)d_in[5];
    const float* baseW = (const float*)d_in[6];
    const float* W1    = (const float*)d_in[7];
    const float* W2    = (const float*)d_in[8];
    const float* gate  = (const float*)d_in[9];
    const float* propW = (const float*)d_in[10];
    const float* propb = (const float*)d_in[11];
    const float* ln2g  = (const float*)d_in[12];
    const float* ln2b  = (const float*)d_in[13];
    const float* outg  = (const float*)d_in[14];
    const float* outb  = (const float*)d_in[15];
    const float* lmW   = (const float*)d_in[16];

    char* ws = (char*)d_ws;
    float* h     = (float*)(ws);                    // 8 MB  [2048][1024] f32
    u16*   hn    = (u16*)  (ws + (8l  << 20));      // 4 MB  [2048][1024] bf16
    float* C     = (float*)(ws + (12l << 20));      // 8 MB  [2048][1024] f32
    u16*   t     = (u16*)  (ws + (20l << 20));      // 8 MB  [2048][2048] bf16 (t[m][k*512+h])
    u16*   W2eff = (u16*)  (ws + (28l << 20));      // 4 MB  [1024][2048] bf16
    float* sc    = (float*)(ws + (32l << 20));      // 16 B

    embed_kernel<<<MM, 256, 0, stream>>>(ids, emb, pos, h);

    for (int l = 0; l < 2; l++) {
        exc_kernel<<<1, 64, 0, stream>>>(propW + l * 16, propb + l * 4, sc);
        ln_bf16_kernel<<<MM, 256, 0, stream>>>(h, hn, ln1g + (long)l * D, ln1b + (long)l * D);
        // base = hn @ base_W[l]^T  (f32 weights staged inline, f32 out into C)
        gemm_kernel<0, true><<<dim3(16, 8, 1), 256, 0, stream>>>(
            hn, baseW + (long)l * D * D, C, nullptr, D, D, D, 0, 0);
        // t[m][k*512+h] = gelu(hn @ W1[l,k]^T), all 4 blocks via grid.z
        gemm_kernel<1, true><<<dim3(16, 4, 4), 256, 0, stream>>>(
            hn, W1 + (long)l * 4 * HH * D, nullptr, t, HH, D, 2048, (long)HH * D, 512);
        // fold gate*exc/sum into W2 (f32 -> scaled bf16)
        scale_w2_kernel<<<2048, 256, 0, stream>>>(
            W2 + (long)l * 4 * D * HH, gate + (long)l * 4 * D, tors, sc, W2eff);
        // C += t @ W2eff^T  (single K=2048 GEMM = combined over all 4 blocks)
        gemm_kernel<2, false><<<dim3(16, 8, 1), 256, 0, stream>>>(
            t, W2eff, C, nullptr, D, 2048, D, 0, 0);
        // h = LN2(h + 0.3*C)
        resln_kernel<<<MM, 256, 0, stream>>>(h, C, ln2g + (long)l * D, ln2b + (long)l * D);
    }

    ln_bf16_kernel<<<MM, 256, 0, stream>>>(h, hn, outg, outb);
    // logits = hn @ lm_head^T -> f32 out (reference output dtype is float32)
    gemm_kernel<0, true><<<dim3(16, 250, 1), 256, 0, stream>>>(
        hn, lmW, (float*)d_out, nullptr, VV, D, VV, 0, 0);
}

// Round 5
// 438.691 us; speedup vs baseline: 1.3348x; 1.3348x over previous
//
#include <hip/hip_runtime.h>
#include <math.h>

typedef unsigned short u16;
typedef short s16x8 __attribute__((ext_vector_type(8)));
typedef float f32x4 __attribute__((ext_vector_type(4)));
typedef u16 u16x4 __attribute__((ext_vector_type(4)));
typedef int i32x4 __attribute__((ext_vector_type(4)));

#define D 1024
#define MM 2048   // B*S
#define HH 512
#define VV 32000

static __device__ __forceinline__ u16 f2bf(float f) {
    union { float f; unsigned int i; } c; c.f = f;
    unsigned int x = c.i;
    return (u16)((x + 0x7fffu + ((x >> 16) & 1u)) >> 16);  // RNE
}
static __device__ __forceinline__ float sigm(float x) { return 1.0f / (1.0f + expf(-x)); }

// async global->LDS, 16B per lane, LDS dest = wave-uniform base + lane*16
static __device__ __forceinline__ void load_lds16(const u16* g, u16* l) {
    __builtin_amdgcn_global_load_lds(
        (const __attribute__((address_space(1))) unsigned int*)g,
        (__attribute__((address_space(3))) unsigned int*)l, 16, 0, 0);
}

// ---------------- f32 -> bf16 convert (grid-stride, vectorized) ----------------
__global__ __launch_bounds__(256) void cvt_kernel(const float* __restrict__ in,
                                                  u16* __restrict__ out, const int n4)
{
    for (int i = blockIdx.x * 256 + threadIdx.x; i < n4; i += gridDim.x * 256) {
        f32x4 v = ((const f32x4*)in)[i];
        u16x4 o;
#pragma unroll
        for (int j = 0; j < 4; j++) o[j] = f2bf(v[j]);
        ((u16x4*)out)[i] = o;
    }
}

// ---------------- embed: h = embedding[ids] + pos (all f32) ----------------
__global__ __launch_bounds__(256) void embed_kernel(const int* __restrict__ ids,
    const float* __restrict__ emb, const float* __restrict__ pos, float* __restrict__ h)
{
    const int m = blockIdx.x;            // 0..2047
    const int s = m & 1023;              // S = 1024
    const long id = ids[m];
    const int d = threadIdx.x * 4;
    f32x4 ev = *(const f32x4*)&emb[id * D + d];
    f32x4 pv = *(const f32x4*)&pos[(long)s * D + d];
    f32x4 o;
#pragma unroll
    for (int i = 0; i < 4; i++) o[i] = ev[i] + pv[i];
    *(f32x4*)&h[(long)m * D + d] = o;
}

// ---------------- layernorm(f32 in) -> bf16 out ----------------
__global__ __launch_bounds__(256) void ln_bf16_kernel(const float* __restrict__ h,
    u16* __restrict__ out, const float* __restrict__ g, const float* __restrict__ b)
{
    const int row = blockIdx.x;
    const int d = threadIdx.x * 4;
    f32x4 x = *(const f32x4*)&h[(long)row * D + d];
    float s = x[0] + x[1] + x[2] + x[3];
    float ss = x[0]*x[0] + x[1]*x[1] + x[2]*x[2] + x[3]*x[3];
#pragma unroll
    for (int off = 32; off; off >>= 1) { s += __shfl_xor(s, off); ss += __shfl_xor(ss, off); }
    __shared__ float red[8];
    const int wid = threadIdx.x >> 6;
    if ((threadIdx.x & 63) == 0) { red[wid] = s; red[4 + wid] = ss; }
    __syncthreads();
    s = red[0] + red[1] + red[2] + red[3];
    ss = red[4] + red[5] + red[6] + red[7];
    const float mu = s * (1.0f / D);
    const float rstd = rsqrtf(ss * (1.0f / D) - mu * mu + 1e-5f);
    f32x4 gv = *(const f32x4*)&g[d];
    f32x4 bv = *(const f32x4*)&b[d];
    u16x4 o;
#pragma unroll
    for (int i = 0; i < 4; i++) o[i] = f2bf((x[i] - mu) * rstd * gv[i] + bv[i]);
    *(u16x4*)&out[(long)row * D + d] = o;
}

// ---------------- h = LN(h + 0.3*C) (f32 in place) ----------------
__global__ __launch_bounds__(256) void resln_kernel(float* __restrict__ h,
    const float* __restrict__ c, const float* __restrict__ g, const float* __restrict__ b)
{
    const int row = blockIdx.x;
    const int d = threadIdx.x * 4;
    f32x4 x = *(const f32x4*)&h[(long)row * D + d];
    f32x4 cv = *(const f32x4*)&c[(long)row * D + d];
#pragma unroll
    for (int i = 0; i < 4; i++) x[i] += 0.3f * cv[i];
    float s = x[0] + x[1] + x[2] + x[3];
    float ss = x[0]*x[0] + x[1]*x[1] + x[2]*x[2] + x[3]*x[3];
#pragma unroll
    for (int off = 32; off; off >>= 1) { s += __shfl_xor(s, off); ss += __shfl_xor(ss, off); }
    __shared__ float red[8];
    const int wid = threadIdx.x >> 6;
    if ((threadIdx.x & 63) == 0) { red[wid] = s; red[4 + wid] = ss; }
    __syncthreads();
    s = red[0] + red[1] + red[2] + red[3];
    ss = red[4] + red[5] + red[6] + red[7];
    const float mu = s * (1.0f / D);
    const float rstd = rsqrtf(ss * (1.0f / D) - mu * mu + 1e-5f);
    f32x4 gv = *(const f32x4*)&g[d];
    f32x4 bv = *(const f32x4*)&b[d];
    f32x4 o;
#pragma unroll
    for (int i = 0; i < 4; i++) o[i] = (x[i] - mu) * rstd * gv[i] + bv[i];
    *(f32x4*)&h[(long)row * D + d] = o;
}

// ---------------- exc scales: sc[k] = exc_k / sum(exc) ----------------
__global__ void exc_kernel(const float* __restrict__ pW, const float* __restrict__ pb,
                           float* __restrict__ sc)
{
    if (threadIdx.x == 0 && blockIdx.x == 0) {
        const float NS = 1.0f / (1.0f + expf(-0.70710678118654752f)); // sigmoid(neighbor infl)
        float e[4], sum = 0.0f;
        for (int k = 0; k < 4; k++) {
            float a = pb[k];
            for (int j = 0; j < 4; j++) a += 0.5f * pW[k * 4 + j];
            e[k] = 0.6f * sigm(a) + 0.4f * NS;
            sum += e[k];
        }
        for (int k = 0; k < 4; k++) sc[k] = e[k] / sum;
    }
}

// ---------------- W2eff[n][k*512+h] = W2[k][n][h] * sigmoid(gate[k][n]+tors[n]) * sc[k] ----------------
__global__ __launch_bounds__(256) void scale_w2_kernel(
    const float* __restrict__ W2l,   // [4][1024][512] f32
    const float* __restrict__ gatel, // [4][1024] f32
    const float* __restrict__ tors,  // [1024] f32
    const float* __restrict__ sc,    // [4]
    u16* __restrict__ W2eff)         // [1024][2048] bf16
{
    const int n = blockIdx.x >> 1;
    const int half = blockIdx.x & 1;
    const int kh = half * 1024 + threadIdx.x * 4;
    const int k = kh >> 9;
    const int hh = kh & 511;
    const float f = sigm(gatel[k * D + n] + tors[n]) * sc[k];
    f32x4 w = *(const f32x4*)&W2l[((long)k * D + n) * HH + hh];
    u16x4 o;
#pragma unroll
    for (int i = 0; i < 4; i++) o[i] = f2bf(w[i] * f);
    *(u16x4*)&W2eff[(long)n * 2048 + kh] = o;
}

// ---------------- GEMM (m97 structure): C[M,N] = A[M,K] @ W[N,K]^T, all bf16 in ----------------
// BM=128 fixed, BN template (128 or 64). 4 waves 2x2. global_load_lds 16B staging, linear LDS.
// EPI: 0 = f32 store, 1 = exact-GELU -> bf16 store, 2 = f32 accumulate (+=)
template<int EPI, int BN>
__global__ __launch_bounds__(256) void gemm_lds_kernel(
    const u16* __restrict__ A, const u16* __restrict__ W,
    float* __restrict__ Cf, u16* __restrict__ Cb,
    const int K, const long ldc, const long strideWz, const long strideCz)
{
    W += (long)blockIdx.z * strideWz;
    if (EPI == 1) Cb += (long)blockIdx.z * strideCz;
    else          Cf += (long)blockIdx.z * strideCz;

    // T1: bijective XCD-chunk swizzle (nwg % 8 == 0 for every launch below).
    // Consecutive hw ids round-robin XCDs; remap so each XCD gets a contiguous
    // logical chunk -> the 16 M-blocks sharing a W panel stay on one XCD's L2.
    const int gx = gridDim.x;
    const int nwg = gx * gridDim.y;
    int lin = blockIdx.y * gx + blockIdx.x;
    lin = (lin & 7) * (nwg >> 3) + (lin >> 3);
    const int bm = (lin % gx) * 128;
    const int bn = (lin / gx) * BN;

    __shared__ __align__(16) u16 As[128 * 32];
    __shared__ __align__(16) u16 Bs[BN * 32];

    const int tid = threadIdx.x;
    const int lane = tid & 63;
    const int w = tid >> 6;
    const int wm = (w >> 1) * 64;          // waves 2x2 over the BMxBN tile
    const int wn = (w & 1) * (BN / 2);
    const int lr = lane & 15;
    const int lkb = (lane >> 4) * 16;      // byte offset of 8-bf16 k-fragment

    const int srow = lane >> 2;            // staging: row within 16-row chunk
    const int scol = (lane & 3) * 8;       // staging: bf16 col (8 per lane = 16B)

    constexpr int NA = 8;                  // 128*64B / 1024B chunks for A
    constexpr int NB = BN / 16;            // chunks for B
    constexpr int NIT = (NA + NB) / 4;     // issues per wave

    f32x4 acc[4][BN / 32];
#pragma unroll
    for (int i = 0; i < 4; i++)
#pragma unroll
        for (int j = 0; j < BN / 32; j++) acc[i][j] = f32x4{0.f, 0.f, 0.f, 0.f};

    for (int k0 = 0; k0 < K; k0 += 32) {
        __syncthreads();   // prev-iter LDS reads done before overwrite
#pragma unroll
        for (int it = 0; it < NIT; ++it) {
            const int c = w + it * 4;      // wave-uniform chunk id
            if (c < NA) {
                load_lds16(&A[(long)(bm + c * 16 + srow) * K + k0 + scol], &As[c * 512]);
            } else {
                const int c2 = c - NA;
                load_lds16(&W[(long)(bn + c2 * 16 + srow) * K + k0 + scol], &Bs[c2 * 512]);
            }
        }
        __syncthreads();   // compiler drains vmcnt(0) before barrier -> LDS ready
        s16x8 a[4], b[BN / 32];
#pragma unroll
        for (int i = 0; i < 4; i++)
            a[i] = *(const s16x8*)((const char*)As + (wm + i * 16 + lr) * 64 + lkb);
#pragma unroll
        for (int j = 0; j < BN / 32; j++)
            b[j] = *(const s16x8*)((const char*)Bs + (wn + j * 16 + lr) * 64 + lkb);
#pragma unroll
        for (int i = 0; i < 4; i++)
#pragma unroll
            for (int j = 0; j < BN / 32; j++)
                acc[i][j] = __builtin_amdgcn_mfma_f32_16x16x32_bf16(a[i], b[j], acc[i][j], 0, 0, 0);
    }

    // C/D layout (verified m89/m91): col = lane&15, row = (lane>>4)*4 + reg
    const int r0 = (lane >> 4) * 4;
#pragma unroll
    for (int i = 0; i < 4; i++) {
#pragma unroll
        for (int j = 0; j < BN / 32; j++) {
            const int n = bn + wn + j * 16 + lr;
#pragma unroll
            for (int r = 0; r < 4; r++) {
                const int m = bm + wm + i * 16 + r0 + r;
                const float v = acc[i][j][r];
                if (EPI == 0) {
                    Cf[(long)m * ldc + n] = v;
                } else if (EPI == 1) {
                    const float gel = 0.5f * v * (1.0f + erff(v * 0.70710678118654752f));
                    Cb[(long)m * ldc + n] = f2bf(gel);
                } else {
                    Cf[(long)m * ldc + n] += v;
                }
            }
        }
    }
}

extern "C" void kernel_launch(void* const* d_in, const int* in_sizes, int n_in,
                              void* d_out, int out_size, void* d_ws, size_t ws_size,
                              hipStream_t stream)
{
    (void)in_sizes; (void)n_in; (void)out_size; (void)ws_size;
    const int*   ids   = (const int*)d_in[0];
    const float* emb   = (const float*)d_in[1];
    const float* pos   = (const float*)d_in[2];
    const float* tors  = (const float*)d_in[3];
    const float* ln1g  = (const float*)d_in[4];
    const float* ln1b  = (const float*)d_in[5];
    const float* baseW = (const float*)d_in[6];
    const float* W1    = (const float*)d_in[7];
    const float* W2    = (const float*)d_in[8];
    const float* gate  = (const float*)d_in[9];
    const float* propW = (const float*)d_in[10];
    const float* propb = (const float*)d_in[11];
    const float* ln2g  = (const float*)d_in[12];
    const float* ln2b  = (const float*)d_in[13];
    const float* outg  = (const float*)d_in[14];
    const float* outb  = (const float*)d_in[15];
    const float* lmW   = (const float*)d_in[16];

    char* ws = (char*)d_ws;
    float* h     = (float*)(ws);                    // 0..8 MB    [2048][1024] f32
    u16*   hn    = (u16*)  (ws + (8l  << 20));      // 8..12 MB   [2048][1024] bf16
    // layer-phase buffers (dead after the loop):
    u16*   bWbf  = (u16*)  (ws + (12l << 20));      // 12..14 MB  [1024][1024] bf16
    u16*   W1bf  = (u16*)  (ws + (14l << 20));      // 14..18 MB  [4][512][1024] bf16
    float* C     = (float*)(ws + (18l << 20));      // 18..26 MB  [2048][1024] f32
    u16*   t     = (u16*)  (ws + (26l << 20));      // 26..34 MB  [2048][2048] bf16
    u16*   W2eff = (u16*)  (ws + (34l << 20));      // 34..38 MB  [1024][2048] bf16
    float* sc    = (float*)(ws + (38l << 20));      // 16 B
    // final-phase buffer, overlaid on the dead layer buffers:
    u16*   lmWbf = (u16*)  (ws + (12l << 20));      // 12..74.5 MB [32000][1024] bf16

    embed_kernel<<<MM, 256, 0, stream>>>(ids, emb, pos, h);

    for (int l = 0; l < 2; l++) {
        exc_kernel<<<1, 64, 0, stream>>>(propW + l * 16, propb + l * 4, sc);
        ln_bf16_kernel<<<MM, 256, 0, stream>>>(h, hn, ln1g + (long)l * D, ln1b + (long)l * D);
        cvt_kernel<<<1024, 256, 0, stream>>>(baseW + (long)l * D * D, bWbf, D * D / 4);
        cvt_kernel<<<2048, 256, 0, stream>>>(W1 + (long)l * 4 * HH * D, W1bf, 4 * HH * D / 4);
        // base = hn @ base_W[l]^T  (f32 into C)
        gemm_lds_kernel<0, 64><<<dim3(16, 16, 1), 256, 0, stream>>>(
            hn, bWbf, C, nullptr, D, D, 0, 0);
        // t[m][k*512+h] = gelu(hn @ W1[l,k]^T), all 4 blocks via grid.z
        gemm_lds_kernel<1, 64><<<dim3(16, 8, 4), 256, 0, stream>>>(
            hn, W1bf, nullptr, t, D, 2048, (long)HH * D, 512);
        // fold gate*exc/sum into W2 (f32 -> scaled bf16)
        scale_w2_kernel<<<2048, 256, 0, stream>>>(
            W2 + (long)l * 4 * D * HH, gate + (long)l * 4 * D, tors, sc, W2eff);
        // C += t @ W2eff^T  (single K=2048 GEMM = combined over all 4 blocks)
        gemm_lds_kernel<2, 64><<<dim3(16, 16, 1), 256, 0, stream>>>(
            t, W2eff, C, nullptr, 2048, D, 0, 0);
        // h = LN2(h + 0.3*C)
        resln_kernel<<<MM, 256, 0, stream>>>(h, C, ln2g + (long)l * D, ln2b + (long)l * D);
    }

    ln_bf16_kernel<<<MM, 256, 0, stream>>>(h, hn, outg, outb);
    // lm_head: convert once to bf16, then logits = hn @ lm_head^T -> f32 out
    cvt_kernel<<<2048, 256, 0, stream>>>(lmW, lmWbf, VV * D / 4);
    gemm_lds_kernel<0, 128><<<dim3(16, 250, 1), 256, 0, stream>>>(
        hn, lmWbf, (float*)d_out, nullptr, D, VV, 0, 0);
}